// Round 18
// baseline (135.445 us; speedup 1.0000x reference)
//
#include <hip/hip_runtime.h>
#include <hip/hip_bf16.h>

#define B_   32
#define L_   2048
#define CIN  256
#define HID  512
#define TL   16
#define TPT  16                    // tiles per block = 256 rows
#define NGRP (B_ * L_ / (TL * TPT))// 256 row-groups of 256 rows
#define NBLK (NGRP * 4)            // x4 G-quarters = 1024 blocks

// 2*log2(e): baked into Wc/bc so the gemm output feeds exp2 directly.
#define TANH_SCALE 2.885390081777927

typedef __bf16 bf16_t;
typedef __bf16 bf16x8 __attribute__((ext_vector_type(8)));
typedef __bf16 bf16x4 __attribute__((ext_vector_type(4)));
typedef float  f32x4  __attribute__((ext_vector_type(4)));

// LDS map (32 KB, packed): buf*16384 + pipe*8192 + row*512 (swizzled rows)
#define APIPE 8192u
#define ABUF  16384u

// ---------------------------------------------------------------------------
// Kernel 1: compose Wc = TANH_SCALE * (W2 @ W1) (fp32 -> bf16),
//           bc = TANH_SCALE * (W2 @ b1 + b2).
// No activation between the two 1x1 convs -> one projection, 3x fewer FLOPs.
// ---------------------------------------------------------------------------
__global__ void compose_kernel(const float* __restrict__ W1, const float* __restrict__ W2,
                               const float* __restrict__ b1, const float* __restrict__ b2,
                               bf16_t* __restrict__ Wc, float* __restrict__ bc)
{
    const int g0 = blockIdx.x * 8;       // 64 blocks
    const int c  = threadIdx.x;          // 256
    float acc[8] = {0.f, 0.f, 0.f, 0.f, 0.f, 0.f, 0.f, 0.f};
    for (int h = 0; h < HID; ++h) {
        const float w1 = W1[(size_t)h * CIN + c];   // coalesced row
#pragma unroll
        for (int k = 0; k < 8; ++k)                 // W2[g0+k][h]: uniform
            acc[k] = fmaf(W2[(size_t)(g0 + k) * HID + h], w1, acc[k]);
    }
#pragma unroll
    for (int k = 0; k < 8; ++k)
        Wc[(size_t)(g0 + k) * CIN + c] = (bf16_t)(acc[k] * (float)TANH_SCALE);
    if (c < 8) {
        const float* w2row = W2 + (size_t)(g0 + c) * HID;
        float t0 = 0.f, t1 = 0.f;
        for (int h = 0; h < HID; h += 2) {
            t0 = fmaf(w2row[h], b1[h], t0);
            t1 = fmaf(w2row[h + 1], b1[h + 1], t1);
        }
        bc[g0 + c] = (t0 + t1 + b2[g0 + c]) * (float)TANH_SCALE;
    }
}

// ---------------------------------------------------------------------------
// Kernel 2: fused GEMM + tanh-pair-product + row-reduction.
// R17's occupancy failure: wreg (64) + acc (16) put true per-wave total at
// ~152 -> 3 waves/SIMD -> only ONE 8-wave block/CU ever resident (21% occ,
// blocks ran in sequential rounds). Fix: G-split x4 -> wave owns 16 cols,
// wreg 32 + acc 8 + arch ~45 = ~85 total -> 6 waves/SIMD tier -> up to 3
// blocks/CU co-resident (LDS 3x32KB=96 <160). launch_bounds (512,5): cap
// 102 regs = spill-proof, still allows the 6-wave tier.
// 1024 blocks x 512 thr. Block (grp, q): 256 rows x 128 cols. Wave w owns
// cols q*128 + w*16 (l4*4+r2 within), rows 0..15 (=l15), both pipes.
// Per tile: [issue v(t+1)] gemm(REG w x LDS a) [swrite v(t+1)] tanh->psum
// bar. x/y dup-read x4 is L3-absorbed (x+y = 128 MB < 256 MB L3; proven
// FETCH=ideal at x2). Weights: one-shot 64 KB L2 read per block.
// ---------------------------------------------------------------------------
__global__ __launch_bounds__(512, 5)
void fused_kernel(const float* __restrict__ x, const float* __restrict__ y,
                  const bf16_t* __restrict__ Wc, const float* __restrict__ bc,
                  float* __restrict__ partial)
{
    __shared__ char U[32768];            // packed A double-buffer

    const int tid  = threadIdx.x;
    const int lane = tid & 63;
    const int wv   = tid >> 6;           // wave 0..7
    const int l15  = lane & 15;
    const int l4   = lane >> 4;
    const int grp  = blockIdx.x >> 2;
    const int q    = blockIdx.x & 3;
    const int gc0  = q * 128 + wv * 16;  // this wave's output-col base

    // --- hoist this wave's weight fragments into registers (32 VGPRs)
    bf16x8 wreg[8];
#pragma unroll
    for (int kk = 0; kk < 8; ++kk)
        wreg[kk] = *reinterpret_cast<const bf16x8*>(
            Wc + (size_t)(gc0 + l15) * CIN + kk * 32 + l4 * 8);

    // bias fragment (scaled), folded into acc init each tile
    f32x4 bcv;
    {
        float4 t4 = *reinterpret_cast<const float4*>(bc + gc0 + l4 * 4);
        bcv = (f32x4){t4.x, t4.y, t4.z, t4.w};
    }

    // staging identity: threads 0-255 stage x, 256-511 stage y; 16 thr/row
    const int sp = tid >> 8;
    const int t8 = tid & 255;
    const int sr = t8 >> 4;              // row 0..15
    const int sq = t8 & 15;              // float4 slot
    const unsigned sswz = (unsigned)((sr & 15) << 4);
    const unsigned soff = (unsigned)(sp * APIPE + sr * 512);
    const float* sptr = (sp ? y : x) + ((size_t)grp * (TPT * TL) + sr) * CIN;

    float4 v[4];
    auto sload = [&](const float* rowbase) {
        const float4* s4 = reinterpret_cast<const float4*>(rowbase);
#pragma unroll
        for (int c = 0; c < 4; ++c) v[c] = s4[sq + 16 * c];
    };
    auto swrite = [&](int buf) {
        char* p = U + (unsigned)(buf * ABUF) + soff;
#pragma unroll
        for (int c = 0; c < 4; ++c) {
            const int f = sq + 16 * c;
            bf16x4 h;
            h[0] = (bf16_t)v[c].x; h[1] = (bf16_t)v[c].y;
            h[2] = (bf16_t)v[c].z; h[3] = (bf16_t)v[c].w;
            *reinterpret_cast<bf16x4*>(p + (((unsigned)(8 * f)) ^ sswz)) = h;
        }
    };

    // A fragment base; per-kk addr = base ^ (kk<<6) (R11/R15-proven swizzle)
    const unsigned abase = (unsigned)(l15 * 512) + (((unsigned)(l4 * 16)) ^ ((unsigned)(l15 << 4)));

    f32x4 psum = (f32x4){0.f, 0.f, 0.f, 0.f};

    // prologue: stage tile 0 into buf 0
    sload(sptr);
    swrite(0);
    __syncthreads();

    int cur = 0;
    for (int t = 0; t < TPT; ++t) {
        const bool pf = (t + 1 < TPT);
        if (pf) {                        // issue tile t+1 loads early (T14)
            sptr += TL * CIN;
            sload(sptr);
        }

        f32x4 accx = bcv, accy = bcv;
        const unsigned ab = (unsigned)(cur * ABUF);
#pragma unroll
        for (int kk = 0; kk < 8; ++kk) {
            const unsigned o = ab + (abase ^ (unsigned)(kk << 6));
            bf16x8 ax = *reinterpret_cast<const bf16x8*>(U + o);
            bf16x8 ay = *reinterpret_cast<const bf16x8*>(U + APIPE + o);
            __builtin_amdgcn_s_setprio(1);
            accx = __builtin_amdgcn_mfma_f32_16x16x32_bf16(wreg[kk], ax, accx, 0, 0, 0);
            accy = __builtin_amdgcn_mfma_f32_16x16x32_bf16(wreg[kk], ay, accy, 0, 0, 0);
            __builtin_amdgcn_s_setprio(0);
        }

        if (pf) swrite(cur ^ 1);         // ds_writes drain under the tanh tail

        // paired tanh product -> psum. Scale baked into Wc/bc: acc IS the
        // exp2 argument. tanh(a)tanh(b) = (Ea-1)(Eb-1)/((Ea+1)(Eb+1)).
#pragma unroll
        for (int r2 = 0; r2 < 4; ++r2) {
            float a = fminf(fmaxf(accx[r2], -26.0f), 26.0f);
            float c = fminf(fmaxf(accy[r2], -26.0f), 26.0f);
            float Ea = exp2f(a);
            float Eb = exp2f(c);
            float num = (Ea - 1.0f) * (Eb - 1.0f);
            float den = (Ea + 1.0f) * (Eb + 1.0f);
            psum[r2] += num * __builtin_amdgcn_rcpf(den);
        }

        __syncthreads();                 // publish buf[cur^1]
        cur ^= 1;
    }

    // reduce over the 16 row-lanes (l15 bits; l4 indexes the col quad)
#pragma unroll
    for (int r2 = 0; r2 < 4; ++r2) {
        float s = psum[r2];
        s += __shfl_xor(s, 1);
        s += __shfl_xor(s, 2);
        s += __shfl_xor(s, 4);
        s += __shfl_xor(s, 8);
        psum[r2] = s;
    }
    if (l15 == 0) {
        float4 o4 = make_float4(psum[0], psum[1], psum[2], psum[3]);
        *reinterpret_cast<float4*>(partial + (size_t)grp * HID + gc0 + l4 * 4) = o4;
    }
}

// ---------------------------------------------------------------------------
// Kernel 3: sum the 8 row-group partials per batch -> out[B][HID]
// (batch = 2048 rows = 8 groups of 256)
// ---------------------------------------------------------------------------
__global__ void reduce_kernel(const float* __restrict__ partial, float* __restrict__ out)
{
    int b = blockIdx.x;                  // 32
    int g = threadIdx.x;                 // 512
    float s = 0.f;
#pragma unroll
    for (int k = 0; k < 8; ++k)
        s += partial[((size_t)(b * 8 + k)) * HID + g];
    out[b * HID + g] = s;
}

extern "C" void kernel_launch(void* const* d_in, const int* in_sizes, int n_in,
                              void* d_out, int out_size, void* d_ws, size_t ws_size,
                              hipStream_t stream)
{
    const float* x  = (const float*)d_in[0];
    const float* y  = (const float*)d_in[1];
    const float* W1 = (const float*)d_in[2];
    const float* b1 = (const float*)d_in[3];
    const float* W2 = (const float*)d_in[4];
    const float* b2 = (const float*)d_in[5];
    float* out = (float*)d_out;

    char* ws = (char*)d_ws;
    bf16_t* Wc     = (bf16_t*)ws;                    // 256 KB
    float*  bc     = (float*)(ws + (256 << 10));     // 2 KB
    float*  partial = (float*)(ws + (264 << 10));    // 512 KB (256 grps x 512)

    hipLaunchKernelGGL(compose_kernel, dim3(HID / 8), dim3(CIN), 0, stream, W1, W2, b1, b2, Wc, bc);
    hipLaunchKernelGGL(fused_kernel, dim3(NBLK), dim3(512), 0, stream, x, y, Wc, bc, partial);
    hipLaunchKernelGGL(reduce_kernel, dim3(B_), dim3(512), 0, stream, partial, out);
}

// Round 19
// 127.103 us; speedup vs baseline: 1.0656x; 1.0656x over previous
//
#include <hip/hip_runtime.h>
#include <hip/hip_bf16.h>

#define B_   32
#define L_   2048
#define CIN  256
#define HID  512
#define TL   16
#define TPT  16                    // tiles per block = 256 rows
#define NGRP 256                   // 256-row groups
#define NBLK (NGRP * 4)            // x4 col-quarters = 1024 blocks

// 2*log2(e): baked into Wc/bc so the gemm output feeds exp2 directly.
#define TANH_SCALE 2.885390081777927

typedef __bf16 bf16_t;
typedef __bf16 bf16x8 __attribute__((ext_vector_type(8)));
typedef __bf16 bf16x4 __attribute__((ext_vector_type(4)));
typedef float  f32x4  __attribute__((ext_vector_type(4)));

// LDS map (20 KB): A tile @0 (x @0, y @8192; row*512, swizzled);
// TY @16384: [wq][cj][l15][l4] bf16x4 = 4 KB.
#define APIPE  8192u
#define TY_OFF 16384u

// ---------------------------------------------------------------------------
// Kernel 1: compose Wc = TANH_SCALE * (W2 @ W1) (fp32 -> bf16),
//           bc = TANH_SCALE * (W2 @ b1 + b2).
// ---------------------------------------------------------------------------
__global__ void compose_kernel(const float* __restrict__ W1, const float* __restrict__ W2,
                               const float* __restrict__ b1, const float* __restrict__ b2,
                               bf16_t* __restrict__ Wc, float* __restrict__ bc)
{
    const int g0 = blockIdx.x * 8;       // 64 blocks
    const int c  = threadIdx.x;          // 256
    float acc[8] = {0.f, 0.f, 0.f, 0.f, 0.f, 0.f, 0.f, 0.f};
    for (int h = 0; h < HID; ++h) {
        const float w1 = W1[(size_t)h * CIN + c];   // coalesced row
#pragma unroll
        for (int k = 0; k < 8; ++k)                 // W2[g0+k][h]: uniform
            acc[k] = fmaf(W2[(size_t)(g0 + k) * HID + h], w1, acc[k]);
    }
#pragma unroll
    for (int k = 0; k < 8; ++k)
        Wc[(size_t)(g0 + k) * CIN + c] = (bf16_t)(acc[k] * (float)TANH_SCALE);
    if (c < 8) {
        const float* w2row = W2 + (size_t)(g0 + c) * HID;
        float t0 = 0.f, t1 = 0.f;
        for (int h = 0; h < HID; h += 2) {
            t0 = fmaf(w2row[h], b1[h], t0);
            t1 = fmaf(w2row[h + 1], b1[h + 1], t1);
        }
        bc[g0 + c] = (t0 + t1 + b2[g0 + c]) * (float)TANH_SCALE;
    }
}

// ---------------------------------------------------------------------------
// Kernel 2: fused GEMM + tanh-pair-product + row-reduction, PIPE-SPLIT.
// R18 diagnosis: 16 cols/wave made MFMA:ds_read = 1:1 -> 41 us of LDS per
// CU (vs 16.6 us MFMA); and the 4 col-split blocks of a grp landed on 4
// XCDs -> duplicate x/y reads missed L2 (FETCH 262 MB).
// Fix 1 (ratio): waves 0-3 = x-pipe, 4-7 = y-pipe; wave owns 32 cols of ONE
// pipe -> wreg 64 + acc 8 (~110 total regs -> 4 waves/SIMD -> 2 blocks/CU)
// and 1 A-read : 2 MFMA (ratio 2, A-LDS cycles halved).
// Fix 2 (tanh pairing): y-waves write tanh(proj_y) bf16 to a 4 KB TY LDS
// buffer; x-waves product it with in-register tanh(proj_x) into psum.
// Fix 3 (XCD): block swizzle d -> (grp,q) with d%8 == grp%8, so all 4
// q-blocks of a grp share one XCD's L2 -> dup reads become L2 hits.
// 2 barriers/tile, single A buffer, 1024 blocks x 512 thr.
// ---------------------------------------------------------------------------
__global__ __launch_bounds__(512, 4)
void fused_kernel(const float* __restrict__ x, const float* __restrict__ y,
                  const bf16_t* __restrict__ Wc, const float* __restrict__ bc,
                  float* __restrict__ partial)
{
    __shared__ char U[20480];

    const int tid  = threadIdx.x;
    const int lane = tid & 63;
    const int wv   = tid >> 6;           // wave 0..7
    const int l15  = lane & 15;
    const int l4   = lane >> 4;

    // XCD-pairing decode: d%8 == grp%8 for all 4 q's of a grp (bijective)
    const int d    = blockIdx.x;
    const int grp  = (d & 7) + 8 * (d >> 5);
    const int q    = (d >> 3) & 3;

    const int pipe = wv >> 2;            // 0 = x-waves, 1 = y-waves
    const int wq   = wv & 3;
    const int gc0  = q * 128 + wq * 32;  // this wave's output-col base

    // --- weight fragments in registers (32 cols, one pipe-agnostic set)
    bf16x8 wreg[8][2];
#pragma unroll
    for (int kk = 0; kk < 8; ++kk)
#pragma unroll
        for (int cj = 0; cj < 2; ++cj)
            wreg[kk][cj] = *reinterpret_cast<const bf16x8*>(
                Wc + (size_t)(gc0 + cj * 16 + l15) * CIN + kk * 32 + l4 * 8);

    // bias fragments (scaled)
    f32x4 bcv[2];
#pragma unroll
    for (int cj = 0; cj < 2; ++cj) {
        float4 t4 = *reinterpret_cast<const float4*>(bc + gc0 + cj * 16 + l4 * 4);
        bcv[cj] = (f32x4){t4.x, t4.y, t4.z, t4.w};
    }

    // staging identity: threads 0-255 stage x, 256-511 stage y; 16 thr/row
    const int sp = tid >> 8;
    const int t8 = tid & 255;
    const int sr = t8 >> 4;              // row 0..15
    const int sq = t8 & 15;              // float4 slot
    const unsigned sswz = (unsigned)((sr & 15) << 4);
    const unsigned soff = (unsigned)(sp * APIPE + sr * 512);
    const float* sptr = (sp ? y : x) + ((size_t)grp * (TPT * TL) + sr) * CIN;

    // A fragment address (own pipe only); per-kk addr = base ^ (kk<<6)
    const unsigned abase = (pipe ? APIPE : 0u) +
        (unsigned)(l15 * 512) + (((unsigned)(l4 * 16)) ^ ((unsigned)(l15 << 4)));
    // TY slot for this wave's 32 cols
    const unsigned tyb = TY_OFF + (unsigned)(wq * 1024 + l15 * 32 + l4 * 8);

    f32x4 psum[2];
    psum[0] = (f32x4){0.f, 0.f, 0.f, 0.f};
    psum[1] = (f32x4){0.f, 0.f, 0.f, 0.f};

    for (int t = 0; t < TPT; ++t) {
        // ---- stage tile t (transient regs only)
        {
            const float4* s4 = reinterpret_cast<const float4*>(sptr);
            float4 v[4];
#pragma unroll
            for (int c = 0; c < 4; ++c) v[c] = s4[sq + 16 * c];
            char* p = U + soff;
#pragma unroll
            for (int c = 0; c < 4; ++c) {
                const int f = sq + 16 * c;
                bf16x4 h;
                h[0] = (bf16_t)v[c].x; h[1] = (bf16_t)v[c].y;
                h[2] = (bf16_t)v[c].z; h[3] = (bf16_t)v[c].w;
                *reinterpret_cast<bf16x4*>(p + (((unsigned)(8 * f)) ^ sswz)) = h;
            }
        }
        __syncthreads();                 // A ready; TY(t-1) consumed

        // ---- gemm own pipe: 1 A-read : 2 MFMA (ratio 2)
        f32x4 acc0 = bcv[0], acc1 = bcv[1];
#pragma unroll
        for (int kk = 0; kk < 8; ++kk) {
            bf16x8 a = *reinterpret_cast<const bf16x8*>(U + (abase ^ (unsigned)(kk << 6)));
            __builtin_amdgcn_s_setprio(1);
            acc0 = __builtin_amdgcn_mfma_f32_16x16x32_bf16(wreg[kk][0], a, acc0, 0, 0, 0);
            acc1 = __builtin_amdgcn_mfma_f32_16x16x32_bf16(wreg[kk][1], a, acc1, 0, 0, 0);
            __builtin_amdgcn_s_setprio(0);
        }

        // ---- tanh own pipe (scale baked in): t = 1 - 2/(exp2(a)+1)
#pragma unroll
        for (int r2 = 0; r2 < 4; ++r2) {
            float a0 = fminf(fmaxf(acc0[r2], -26.0f), 26.0f);
            float a1 = fminf(fmaxf(acc1[r2], -26.0f), 26.0f);
            acc0[r2] = fmaf(-2.0f, __builtin_amdgcn_rcpf(exp2f(a0) + 1.0f), 1.0f);
            acc1[r2] = fmaf(-2.0f, __builtin_amdgcn_rcpf(exp2f(a1) + 1.0f), 1.0f);
        }

        if (pipe) {                      // y-waves: publish tanh as bf16
            bf16x4 t0, t1;
#pragma unroll
            for (int r2 = 0; r2 < 4; ++r2) { t0[r2] = (bf16_t)acc0[r2]; t1[r2] = (bf16_t)acc1[r2]; }
            *reinterpret_cast<bf16x4*>(U + tyb)        = t0;
            *reinterpret_cast<bf16x4*>(U + tyb + 512u) = t1;
        }
        __syncthreads();                 // TY ready; A reads done

        if (!pipe) {                     // x-waves: product into psum
            bf16x4 o0 = *reinterpret_cast<const bf16x4*>(U + tyb);
            bf16x4 o1 = *reinterpret_cast<const bf16x4*>(U + tyb + 512u);
#pragma unroll
            for (int r2 = 0; r2 < 4; ++r2) {
                psum[0][r2] = fmaf(acc0[r2], (float)o0[r2], psum[0][r2]);
                psum[1][r2] = fmaf(acc1[r2], (float)o1[r2], psum[1][r2]);
            }
        }
        sptr += TL * CIN;
    }

    // x-waves: reduce over the 16 row-lanes and store
    if (!pipe) {
#pragma unroll
        for (int cj = 0; cj < 2; ++cj)
#pragma unroll
            for (int r2 = 0; r2 < 4; ++r2) {
                float s = psum[cj][r2];
                s += __shfl_xor(s, 1);
                s += __shfl_xor(s, 2);
                s += __shfl_xor(s, 4);
                s += __shfl_xor(s, 8);
                psum[cj][r2] = s;
            }
        if (l15 == 0) {
#pragma unroll
            for (int cj = 0; cj < 2; ++cj) {
                float4 o4 = make_float4(psum[cj][0], psum[cj][1], psum[cj][2], psum[cj][3]);
                *reinterpret_cast<float4*>(partial + (size_t)grp * HID + gc0 + cj * 16 + l4 * 4) = o4;
            }
        }
    }
}

// ---------------------------------------------------------------------------
// Kernel 3: sum the 8 row-group partials per batch -> out[B][HID]
// ---------------------------------------------------------------------------
__global__ void reduce_kernel(const float* __restrict__ partial, float* __restrict__ out)
{
    int b = blockIdx.x;                  // 32
    int g = threadIdx.x;                 // 512
    float s = 0.f;
#pragma unroll
    for (int k = 0; k < 8; ++k)
        s += partial[((size_t)(b * 8 + k)) * HID + g];
    out[b * HID + g] = s;
}

extern "C" void kernel_launch(void* const* d_in, const int* in_sizes, int n_in,
                              void* d_out, int out_size, void* d_ws, size_t ws_size,
                              hipStream_t stream)
{
    const float* x  = (const float*)d_in[0];
    const float* y  = (const float*)d_in[1];
    const float* W1 = (const float*)d_in[2];
    const float* b1 = (const float*)d_in[3];
    const float* W2 = (const float*)d_in[4];
    const float* b2 = (const float*)d_in[5];
    float* out = (float*)d_out;

    char* ws = (char*)d_ws;
    bf16_t* Wc     = (bf16_t*)ws;                    // 256 KB
    float*  bc     = (float*)(ws + (256 << 10));     // 2 KB
    float*  partial = (float*)(ws + (264 << 10));    // 512 KB (256 grps x 512)

    hipLaunchKernelGGL(compose_kernel, dim3(HID / 8), dim3(CIN), 0, stream, W1, W2, b1, b2, Wc, bc);
    hipLaunchKernelGGL(fused_kernel, dim3(NBLK), dim3(512), 0, stream, x, y, Wc, bc, partial);
    hipLaunchKernelGGL(reduce_kernel, dim3(B_), dim3(512), 0, stream, partial, out);
}

// Round 20
// 113.673 us; speedup vs baseline: 1.1915x; 1.1181x over previous
//
#include <hip/hip_runtime.h>
#include <hip/hip_bf16.h>

#define B_   32
#define L_   2048
#define CIN  256
#define HID  512
#define TL   16
#define TPT  32                    // tiles per block = 512 rows
#define NGRP 128                   // 512-row groups
#define NBLK (NGRP * 4)            // x4 col-quarters = 512 blocks = 2/CU

// 2*log2(e): baked into Wc/bc so the gemm output feeds exp2 directly.
#define TANH_SCALE 2.885390081777927

typedef __bf16 bf16_t;
typedef __bf16 bf16x8 __attribute__((ext_vector_type(8)));
typedef __bf16 bf16x4 __attribute__((ext_vector_type(4)));
typedef float  f32x4  __attribute__((ext_vector_type(4)));

// LDS map (48 KB):
//   A dbuf @0:      buf*16384 + pipe*8192 + row*512 (swizzled rows)
//   TY dbuf @32768: buf*8192 + wq*1536 + cj*768 + l15*48 + l4*8  (<=2-way)
#define APIPE  8192u
#define ABUF   16384u
#define TY_OFF 32768u

// ---------------------------------------------------------------------------
// Kernel 1: compose Wc = TANH_SCALE * (W2 @ W1) (fp32 -> bf16),
//           bc = TANH_SCALE * (W2 @ b1 + b2).
// ---------------------------------------------------------------------------
__global__ void compose_kernel(const float* __restrict__ W1, const float* __restrict__ W2,
                               const float* __restrict__ b1, const float* __restrict__ b2,
                               bf16_t* __restrict__ Wc, float* __restrict__ bc)
{
    const int g0 = blockIdx.x * 8;       // 64 blocks
    const int c  = threadIdx.x;          // 256
    float acc[8] = {0.f, 0.f, 0.f, 0.f, 0.f, 0.f, 0.f, 0.f};
    for (int h = 0; h < HID; ++h) {
        const float w1 = W1[(size_t)h * CIN + c];   // coalesced row
#pragma unroll
        for (int k = 0; k < 8; ++k)                 // W2[g0+k][h]: uniform
            acc[k] = fmaf(W2[(size_t)(g0 + k) * HID + h], w1, acc[k]);
    }
#pragma unroll
    for (int k = 0; k < 8; ++k)
        Wc[(size_t)(g0 + k) * CIN + c] = (bf16_t)(acc[k] * (float)TANH_SCALE);
    if (c < 8) {
        const float* w2row = W2 + (size_t)(g0 + c) * HID;
        float t0 = 0.f, t1 = 0.f;
        for (int h = 0; h < HID; h += 2) {
            t0 = fmaf(w2row[h], b1[h], t0);
            t1 = fmaf(w2row[h + 1], b1[h + 1], t1);
        }
        bc[g0 + c] = (t0 + t1 + b2[g0 + c]) * (float)TANH_SCALE;
    }
}

// ---------------------------------------------------------------------------
// Kernel 2: fused GEMM + tanh-pair-product + row-reduction.
// = R19 (pipe-split ratio-2 gemm, XCD pairing, wreg hoist) with the three
// regressions fixed:
//  (a) A double-buffer + T14 prefetch: v[4] issued at tile top, swrite into
//      the idle buffer before the barrier -> HBM latency hides under gemm.
//  (b) TY double-buffered (1 barrier/tile, no race) + 48B row stride
//      (<=2-way, free; the 32B stride was a 4-way conflict, 3.1M cycles).
//  (c) TPT=32 -> 512 blocks = exactly 2/CU resident, single dispatch round.
// tanh clamps dropped: exp2->inf/0 saturates tanh to +-1 gracefully.
// Ledger: wreg 64 + acc 8 + arch (v 16, psum 8, bcv 8, ptrs ~20) ~= 124
// <= 128 -> 4 waves/SIMD tier (tripwire: OccupancyPercent ~50 vs 39).
// ---------------------------------------------------------------------------
__global__ __launch_bounds__(512, 4)
void fused_kernel(const float* __restrict__ x, const float* __restrict__ y,
                  const bf16_t* __restrict__ Wc, const float* __restrict__ bc,
                  float* __restrict__ partial)
{
    __shared__ char U[49152];

    const int tid  = threadIdx.x;
    const int lane = tid & 63;
    const int wv   = tid >> 6;           // wave 0..7
    const int l15  = lane & 15;
    const int l4   = lane >> 4;

    // XCD-pairing decode: d%8 == grp%8 for all 4 q's of a grp (bijective,
    // NBLK=512: grp = (d&7)+8*(d>>5) in 0..127, q = (d>>3)&3)
    const int d    = blockIdx.x;
    const int grp  = (d & 7) + 8 * (d >> 5);
    const int q    = (d >> 3) & 3;

    const int pipe = wv >> 2;            // 0 = x-waves, 1 = y-waves
    const int wq   = wv & 3;
    const int gc0  = q * 128 + wq * 32;  // this wave's output-col base

    // --- weight fragments in registers (32 cols of the composed Wc)
    bf16x8 wreg[8][2];
#pragma unroll
    for (int kk = 0; kk < 8; ++kk)
#pragma unroll
        for (int cj = 0; cj < 2; ++cj)
            wreg[kk][cj] = *reinterpret_cast<const bf16x8*>(
                Wc + (size_t)(gc0 + cj * 16 + l15) * CIN + kk * 32 + l4 * 8);

    // bias fragments (scaled)
    f32x4 bcv[2];
#pragma unroll
    for (int cj = 0; cj < 2; ++cj) {
        float4 t4 = *reinterpret_cast<const float4*>(bc + gc0 + cj * 16 + l4 * 4);
        bcv[cj] = (f32x4){t4.x, t4.y, t4.z, t4.w};
    }

    // staging identity: threads 0-255 stage x, 256-511 stage y; 16 thr/row
    const int sp = tid >> 8;
    const int t8 = tid & 255;
    const int sr = t8 >> 4;              // row 0..15
    const int sq = t8 & 15;              // float4 slot
    const unsigned sswz = (unsigned)((sr & 15) << 4);
    const unsigned soff = (unsigned)(sp * APIPE + sr * 512);
    const float* sptr = (sp ? y : x) + ((size_t)grp * (TPT * TL) + sr) * CIN;

    float4 v[4];
    auto sload = [&](const float* rowbase) {
        const float4* s4 = reinterpret_cast<const float4*>(rowbase);
#pragma unroll
        for (int c = 0; c < 4; ++c) v[c] = s4[sq + 16 * c];
    };
    auto swrite = [&](int buf) {
        char* p = U + (unsigned)(buf * ABUF) + soff;
#pragma unroll
        for (int c = 0; c < 4; ++c) {
            const int f = sq + 16 * c;
            bf16x4 h;
            h[0] = (bf16_t)v[c].x; h[1] = (bf16_t)v[c].y;
            h[2] = (bf16_t)v[c].z; h[3] = (bf16_t)v[c].w;
            *reinterpret_cast<bf16x4*>(p + (((unsigned)(8 * f)) ^ sswz)) = h;
        }
    };

    // A fragment address (own pipe); per-kk addr = base ^ (kk<<6)
    const unsigned abase = (pipe ? APIPE : 0u) +
        (unsigned)(l15 * 512) + (((unsigned)(l4 * 16)) ^ ((unsigned)(l15 << 4)));
    // TY slot (dbuf handled by +buf*8192)
    const unsigned tyb = TY_OFF + (unsigned)(wq * 1536 + l15 * 48 + l4 * 8);

    f32x4 psum[2];
    psum[0] = (f32x4){0.f, 0.f, 0.f, 0.f};
    psum[1] = (f32x4){0.f, 0.f, 0.f, 0.f};

    // prologue: stage tile 0 into buf 0
    sload(sptr);
    swrite(0);
    __syncthreads();

    for (int t = 0; t < TPT; ++t) {
        const bool pf = (t + 1 < TPT);
        const int cur = t & 1;
        if (pf) {                        // issue tile t+1 loads early (T14)
            sptr += TL * CIN;
            sload(sptr);
        }

        // ---- gemm own pipe: 1 A-read : 2 MFMA
        f32x4 acc0 = bcv[0], acc1 = bcv[1];
        const unsigned ab = abase + (unsigned)(cur * ABUF);
#pragma unroll
        for (int kk = 0; kk < 8; ++kk) {
            bf16x8 a = *reinterpret_cast<const bf16x8*>(U + (ab ^ (unsigned)(kk << 6)));
            __builtin_amdgcn_s_setprio(1);
            acc0 = __builtin_amdgcn_mfma_f32_16x16x32_bf16(wreg[kk][0], a, acc0, 0, 0, 0);
            acc1 = __builtin_amdgcn_mfma_f32_16x16x32_bf16(wreg[kk][1], a, acc1, 0, 0, 0);
            __builtin_amdgcn_s_setprio(0);
        }

        // ---- tanh own pipe (scale baked in): t = 1 - 2/(exp2(a)+1);
        // no clamps: exp2 saturates to inf/0 -> tanh saturates to +-1.
#pragma unroll
        for (int r2 = 0; r2 < 4; ++r2) {
            acc0[r2] = fmaf(-2.0f, __builtin_amdgcn_rcpf(exp2f(acc0[r2]) + 1.0f), 1.0f);
            acc1[r2] = fmaf(-2.0f, __builtin_amdgcn_rcpf(exp2f(acc1[r2]) + 1.0f), 1.0f);
        }

        if (pipe) {                      // y-waves: publish tanh as bf16
            bf16x4 t0, t1;
#pragma unroll
            for (int r2 = 0; r2 < 4; ++r2) { t0[r2] = (bf16_t)acc0[r2]; t1[r2] = (bf16_t)acc1[r2]; }
            *reinterpret_cast<bf16x4*>(U + tyb + (unsigned)(cur * 8192))         = t0;
            *reinterpret_cast<bf16x4*>(U + tyb + (unsigned)(cur * 8192) + 768u)  = t1;
        }

        if (pf) swrite(cur ^ 1);         // A(t+1) into the idle buffer

        __syncthreads();                 // publish TY[cur] + A[cur^1]

        if (!pipe) {                     // x-waves: product into psum
            bf16x4 o0 = *reinterpret_cast<const bf16x4*>(U + tyb + (unsigned)(cur * 8192));
            bf16x4 o1 = *reinterpret_cast<const bf16x4*>(U + tyb + (unsigned)(cur * 8192) + 768u);
#pragma unroll
            for (int r2 = 0; r2 < 4; ++r2) {
                psum[0][r2] = fmaf(acc0[r2], (float)o0[r2], psum[0][r2]);
                psum[1][r2] = fmaf(acc1[r2], (float)o1[r2], psum[1][r2]);
            }
        }
    }

    // x-waves: reduce over the 16 row-lanes and store
    if (!pipe) {
#pragma unroll
        for (int cj = 0; cj < 2; ++cj)
#pragma unroll
            for (int r2 = 0; r2 < 4; ++r2) {
                float s = psum[cj][r2];
                s += __shfl_xor(s, 1);
                s += __shfl_xor(s, 2);
                s += __shfl_xor(s, 4);
                s += __shfl_xor(s, 8);
                psum[cj][r2] = s;
            }
        if (l15 == 0) {
#pragma unroll
            for (int cj = 0; cj < 2; ++cj) {
                float4 o4 = make_float4(psum[cj][0], psum[cj][1], psum[cj][2], psum[cj][3]);
                *reinterpret_cast<float4*>(partial + (size_t)grp * HID + gc0 + cj * 16 + l4 * 4) = o4;
            }
        }
    }
}

// ---------------------------------------------------------------------------
// Kernel 3: sum the 4 row-group partials per batch -> out[B][HID]
// (batch = 2048 rows = 4 groups of 512)
// ---------------------------------------------------------------------------
__global__ void reduce_kernel(const float* __restrict__ partial, float* __restrict__ out)
{
    int b = blockIdx.x;                  // 32
    int g = threadIdx.x;                 // 512
    float s = 0.f;
#pragma unroll
    for (int k = 0; k < 4; ++k)
        s += partial[((size_t)(b * 4 + k)) * HID + g];
    out[b * HID + g] = s;
}

extern "C" void kernel_launch(void* const* d_in, const int* in_sizes, int n_in,
                              void* d_out, int out_size, void* d_ws, size_t ws_size,
                              hipStream_t stream)
{
    const float* x  = (const float*)d_in[0];
    const float* y  = (const float*)d_in[1];
    const float* W1 = (const float*)d_in[2];
    const float* b1 = (const float*)d_in[3];
    const float* W2 = (const float*)d_in[4];
    const float* b2 = (const float*)d_in[5];
    float* out = (float*)d_out;

    char* ws = (char*)d_ws;
    bf16_t* Wc     = (bf16_t*)ws;                    // 256 KB
    float*  bc     = (float*)(ws + (256 << 10));     // 2 KB
    float*  partial = (float*)(ws + (264 << 10));    // 256 KB (128 grps x 512)

    hipLaunchKernelGGL(compose_kernel, dim3(HID / 8), dim3(CIN), 0, stream, W1, W2, b1, b2, Wc, bc);
    hipLaunchKernelGGL(fused_kernel, dim3(NBLK), dim3(512), 0, stream, x, y, Wc, bc, partial);
    hipLaunchKernelGGL(reduce_kernel, dim3(B_), dim3(512), 0, stream, partial, out);
}

// Round 21
// 89.538 us; speedup vs baseline: 1.5127x; 1.2695x over previous
//
#include <hip/hip_runtime.h>
#include <hip/hip_bf16.h>

#define B_   32
#define L_   2048
#define CIN  256
#define HID  512
#define TL   16
#define TPT  16                    // tiles per block = 256 rows
#define NGRP 256                   // 256-row groups
#define NBLK (NGRP * 4)            // x4 col-quarters = 1024 blocks = 4/CU

// 2*log2(e): baked into Wc/bc so the gemm output feeds exp2 directly.
#define TANH_SCALE 2.885390081777927

typedef __bf16 bf16_t;
typedef __bf16 bf16x8 __attribute__((ext_vector_type(8)));
typedef __bf16 bf16x4 __attribute__((ext_vector_type(4)));
typedef float  f32x4  __attribute__((ext_vector_type(4)));

// LDS map (48 KB):
//   A dbuf @0:      buf*16384 + pipe*8192 + row*512 (swizzled rows)
//   TY dbuf @32768: buf*8192 + wq*1536 + cj*768 + l15*48 + l4*8  (<=2-way)
#define APIPE  8192u
#define ABUF   16384u
#define TY_OFF 32768u

// ---------------------------------------------------------------------------
// Kernel 1: compose Wc = TANH_SCALE * (W2 @ W1) (fp32 -> bf16),
//           bc = TANH_SCALE * (W2 @ b1 + b2).
// R11-proven shape: 512 blocks (one g-row each) x 256 threads, 8 independent
// fma chains -> 8 W1-row loads in flight, 8 waves/CU. The R14 64-block
// variant was a serial 512-load latency chain at 1 wave/SIMD: 73 us of
// hidden critical path (R20 profile #1).
// ---------------------------------------------------------------------------
__global__ void compose_kernel(const float* __restrict__ W1, const float* __restrict__ W2,
                               const float* __restrict__ b1, const float* __restrict__ b2,
                               bf16_t* __restrict__ Wc, float* __restrict__ bc)
{
    const int g = blockIdx.x;            // 512
    const int c = threadIdx.x;           // 256
    const float* w2row = W2 + (size_t)g * HID;
    float s[8] = {0.f, 0.f, 0.f, 0.f, 0.f, 0.f, 0.f, 0.f};
    for (int h = 0; h < HID; h += 8) {
#pragma unroll
        for (int k = 0; k < 8; ++k)
            s[k] = fmaf(w2row[h + k], W1[(size_t)(h + k) * CIN + c], s[k]);
    }
    float tot = ((s[0] + s[1]) + (s[2] + s[3])) + ((s[4] + s[5]) + (s[6] + s[7]));
    Wc[(size_t)g * CIN + c] = (bf16_t)(tot * (float)TANH_SCALE);
    if (c == 0) {
        float t0 = 0.f, t1 = 0.f;
        for (int h = 0; h < HID; h += 2) {
            t0 = fmaf(w2row[h], b1[h], t0);
            t1 = fmaf(w2row[h + 1], b1[h + 1], t1);
        }
        bc[g] = (t0 + t1 + b2[g]) * (float)TANH_SCALE;
    }
}

// ---------------------------------------------------------------------------
// Kernel 2: fused GEMM + tanh-pair-product + row-reduction.
// R20 structure (pipe-split ratio-2 gemm, XCD pairing, A dbuf + T14
// prefetch, TY dbuf) with TPT=16 -> 1024 blocks = 4/CU, 3 co-resident by
// LDS (3x48=144<=160 KB; regs ~72 total are no limit) -> occupancy up from
// 36% and more cross-block overlap for the trans-heavy tanh + LDS phases.
// setprio hoisted around the whole kk loop.
// ---------------------------------------------------------------------------
__global__ __launch_bounds__(512, 4)
void fused_kernel(const float* __restrict__ x, const float* __restrict__ y,
                  const bf16_t* __restrict__ Wc, const float* __restrict__ bc,
                  float* __restrict__ partial)
{
    __shared__ char U[49152];

    const int tid  = threadIdx.x;
    const int lane = tid & 63;
    const int wv   = tid >> 6;           // wave 0..7
    const int l15  = lane & 15;
    const int l4   = lane >> 4;

    // XCD-pairing decode: d%8 == grp%8 for all 4 q's of a grp (bijective:
    // d = 32*(d>>5) + 8*q + (d&7); grp in 0..255, q in 0..3)
    const int d    = blockIdx.x;
    const int grp  = (d & 7) + 8 * (d >> 5);
    const int q    = (d >> 3) & 3;

    const int pipe = wv >> 2;            // 0 = x-waves, 1 = y-waves
    const int wq   = wv & 3;
    const int gc0  = q * 128 + wq * 32;  // this wave's output-col base

    // --- weight fragments (compiler keeps or reloads from L1/L2 per tile)
    bf16x8 wreg[8][2];
#pragma unroll
    for (int kk = 0; kk < 8; ++kk)
#pragma unroll
        for (int cj = 0; cj < 2; ++cj)
            wreg[kk][cj] = *reinterpret_cast<const bf16x8*>(
                Wc + (size_t)(gc0 + cj * 16 + l15) * CIN + kk * 32 + l4 * 8);

    // bias fragments (scaled)
    f32x4 bcv[2];
#pragma unroll
    for (int cj = 0; cj < 2; ++cj) {
        float4 t4 = *reinterpret_cast<const float4*>(bc + gc0 + cj * 16 + l4 * 4);
        bcv[cj] = (f32x4){t4.x, t4.y, t4.z, t4.w};
    }

    // staging identity: threads 0-255 stage x, 256-511 stage y; 16 thr/row
    const int sp = tid >> 8;
    const int t8 = tid & 255;
    const int sr = t8 >> 4;              // row 0..15
    const int sq = t8 & 15;              // float4 slot
    const unsigned sswz = (unsigned)((sr & 15) << 4);
    const unsigned soff = (unsigned)(sp * APIPE + sr * 512);
    const float* sptr = (sp ? y : x) + ((size_t)grp * (TPT * TL) + sr) * CIN;

    float4 v[4];
    auto sload = [&](const float* rowbase) {
        const float4* s4 = reinterpret_cast<const float4*>(rowbase);
#pragma unroll
        for (int c = 0; c < 4; ++c) v[c] = s4[sq + 16 * c];
    };
    auto swrite = [&](int buf) {
        char* p = U + (unsigned)(buf * ABUF) + soff;
#pragma unroll
        for (int c = 0; c < 4; ++c) {
            const int f = sq + 16 * c;
            bf16x4 h;
            h[0] = (bf16_t)v[c].x; h[1] = (bf16_t)v[c].y;
            h[2] = (bf16_t)v[c].z; h[3] = (bf16_t)v[c].w;
            *reinterpret_cast<bf16x4*>(p + (((unsigned)(8 * f)) ^ sswz)) = h;
        }
    };

    // A fragment address (own pipe); per-kk addr = base ^ (kk<<6)
    const unsigned abase = (pipe ? APIPE : 0u) +
        (unsigned)(l15 * 512) + (((unsigned)(l4 * 16)) ^ ((unsigned)(l15 << 4)));
    // TY slot (dbuf handled by +buf*8192)
    const unsigned tyb = TY_OFF + (unsigned)(wq * 1536 + l15 * 48 + l4 * 8);

    f32x4 psum[2];
    psum[0] = (f32x4){0.f, 0.f, 0.f, 0.f};
    psum[1] = (f32x4){0.f, 0.f, 0.f, 0.f};

    // prologue: stage tile 0 into buf 0
    sload(sptr);
    swrite(0);
    __syncthreads();

    for (int t = 0; t < TPT; ++t) {
        const bool pf = (t + 1 < TPT);
        const int cur = t & 1;
        if (pf) {                        // issue tile t+1 loads early (T14)
            sptr += TL * CIN;
            sload(sptr);
        }

        // ---- gemm own pipe: 1 A-read : 2 MFMA
        f32x4 acc0 = bcv[0], acc1 = bcv[1];
        const unsigned ab = abase + (unsigned)(cur * ABUF);
        __builtin_amdgcn_s_setprio(1);
#pragma unroll
        for (int kk = 0; kk < 8; ++kk) {
            bf16x8 a = *reinterpret_cast<const bf16x8*>(U + (ab ^ (unsigned)(kk << 6)));
            acc0 = __builtin_amdgcn_mfma_f32_16x16x32_bf16(wreg[kk][0], a, acc0, 0, 0, 0);
            acc1 = __builtin_amdgcn_mfma_f32_16x16x32_bf16(wreg[kk][1], a, acc1, 0, 0, 0);
        }
        __builtin_amdgcn_s_setprio(0);

        // ---- tanh own pipe (scale baked in): t = 1 - 2/(exp2(a)+1);
        // no clamps: exp2 saturates to inf/0 -> tanh saturates to +-1.
#pragma unroll
        for (int r2 = 0; r2 < 4; ++r2) {
            acc0[r2] = fmaf(-2.0f, __builtin_amdgcn_rcpf(exp2f(acc0[r2]) + 1.0f), 1.0f);
            acc1[r2] = fmaf(-2.0f, __builtin_amdgcn_rcpf(exp2f(acc1[r2]) + 1.0f), 1.0f);
        }

        if (pipe) {                      // y-waves: publish tanh as bf16
            bf16x4 t0, t1;
#pragma unroll
            for (int r2 = 0; r2 < 4; ++r2) { t0[r2] = (bf16_t)acc0[r2]; t1[r2] = (bf16_t)acc1[r2]; }
            *reinterpret_cast<bf16x4*>(U + tyb + (unsigned)(cur * 8192))        = t0;
            *reinterpret_cast<bf16x4*>(U + tyb + (unsigned)(cur * 8192) + 768u) = t1;
        }

        if (pf) swrite(cur ^ 1);         // A(t+1) into the idle buffer

        __syncthreads();                 // publish TY[cur] + A[cur^1]

        if (!pipe) {                     // x-waves: product into psum
            bf16x4 o0 = *reinterpret_cast<const bf16x4*>(U + tyb + (unsigned)(cur * 8192));
            bf16x4 o1 = *reinterpret_cast<const bf16x4*>(U + tyb + (unsigned)(cur * 8192) + 768u);
#pragma unroll
            for (int r2 = 0; r2 < 4; ++r2) {
                psum[0][r2] = fmaf(acc0[r2], (float)o0[r2], psum[0][r2]);
                psum[1][r2] = fmaf(acc1[r2], (float)o1[r2], psum[1][r2]);
            }
        }
    }

    // x-waves: reduce over the 16 row-lanes and store
    if (!pipe) {
#pragma unroll
        for (int cj = 0; cj < 2; ++cj)
#pragma unroll
            for (int r2 = 0; r2 < 4; ++r2) {
                float s = psum[cj][r2];
                s += __shfl_xor(s, 1);
                s += __shfl_xor(s, 2);
                s += __shfl_xor(s, 4);
                s += __shfl_xor(s, 8);
                psum[cj][r2] = s;
            }
        if (l15 == 0) {
#pragma unroll
            for (int cj = 0; cj < 2; ++cj) {
                float4 o4 = make_float4(psum[cj][0], psum[cj][1], psum[cj][2], psum[cj][3]);
                *reinterpret_cast<float4*>(partial + (size_t)grp * HID + gc0 + cj * 16 + l4 * 4) = o4;
            }
        }
    }
}

// ---------------------------------------------------------------------------
// Kernel 3: sum the 8 row-group partials per batch -> out[B][HID]
// (batch = 2048 rows = 8 groups of 256)
// ---------------------------------------------------------------------------
__global__ void reduce_kernel(const float* __restrict__ partial, float* __restrict__ out)
{
    int b = blockIdx.x;                  // 32
    int g = threadIdx.x;                 // 512
    float s = 0.f;
#pragma unroll
    for (int k = 0; k < 8; ++k)
        s += partial[((size_t)(b * 8 + k)) * HID + g];
    out[b * HID + g] = s;
}

extern "C" void kernel_launch(void* const* d_in, const int* in_sizes, int n_in,
                              void* d_out, int out_size, void* d_ws, size_t ws_size,
                              hipStream_t stream)
{
    const float* x  = (const float*)d_in[0];
    const float* y  = (const float*)d_in[1];
    const float* W1 = (const float*)d_in[2];
    const float* b1 = (const float*)d_in[3];
    const float* W2 = (const float*)d_in[4];
    const float* b2 = (const float*)d_in[5];
    float* out = (float*)d_out;

    char* ws = (char*)d_ws;
    bf16_t* Wc     = (bf16_t*)ws;                    // 256 KB
    float*  bc     = (float*)(ws + (256 << 10));     // 2 KB
    float*  partial = (float*)(ws + (264 << 10));    // 512 KB (256 grps x 512)

    hipLaunchKernelGGL(compose_kernel, dim3(HID), dim3(CIN), 0, stream, W1, W2, b1, b2, Wc, bc);
    hipLaunchKernelGGL(fused_kernel, dim3(NBLK), dim3(512), 0, stream, x, y, Wc, bc, partial);
    hipLaunchKernelGGL(reduce_kernel, dim3(B_), dim3(512), 0, stream, partial, out);
}